// Round 1
// baseline (1101.015 us; speedup 1.0000x reference)
//
#include <hip/hip_runtime.h>

#define D 128

// ---------------------------------------------------------------------------
// deg[v] = 1.0 (self-loop)
__global__ void k_deg_init(float* __restrict__ deg, int N) {
    int i = blockIdx.x * blockDim.x + threadIdx.x;
    if (i < N) deg[i] = 1.0f;
}

// deg[dst[e]] += 1 per edge
__global__ void k_deg_count(const int* __restrict__ dst, float* __restrict__ deg, int E) {
    int i = blockIdx.x * blockDim.x + threadIdx.x;
    if (i < E) atomicAdd(&deg[dst[i]], 1.0f);
}

// in-place: deg -> rsqrt(deg)   (deg >= 1 always, self-loop guarantees it)
__global__ void k_dinv(float* __restrict__ deg, int N) {
    int i = blockIdx.x * blockDim.x + threadIdx.x;
    if (i < N) deg[i] = rsqrtf(deg[i]);
}

// ---------------------------------------------------------------------------
// hs[n,:] = (x[n,:] @ W) * dinv[n];  acc initialized to hs (self-loop term).
// Block: 256 threads, 16 rows per block. Thread (d = tid&127, rg = tid>>7)
// computes rows rg*8 .. rg*8+7 at column d. x tile staged in LDS; W stays in
// L1/L2 (64 KB, reused by all blocks).
#define GEMM_ROWS 16
__global__ __launch_bounds__(256) void k_gemm(const float* __restrict__ x,
                                              const float* __restrict__ W,
                                              const float* __restrict__ dinv,
                                              float* __restrict__ hs,
                                              float* __restrict__ acc, int N) {
    __shared__ float xs[GEMM_ROWS][D];
    const int row0 = blockIdx.x * GEMM_ROWS;

    // cooperative load of the x tile (zero-pad past N)
    for (int t = threadIdx.x; t < GEMM_ROWS * D; t += 256) {
        int r = t >> 7, c = t & 127;
        int gr = row0 + r;
        xs[r][c] = (gr < N) ? x[(size_t)gr * D + c] : 0.0f;
    }
    __syncthreads();

    const int d  = threadIdx.x & 127;
    const int rg = threadIdx.x >> 7;   // 0 or 1

    float accv[8];
#pragma unroll
    for (int j = 0; j < 8; ++j) accv[j] = 0.0f;

    for (int k = 0; k < D; ++k) {
        float w = W[(size_t)k * D + d];
#pragma unroll
        for (int j = 0; j < 8; ++j)
            accv[j] = fmaf(xs[rg * 8 + j][k], w, accv[j]);
    }

#pragma unroll
    for (int j = 0; j < 8; ++j) {
        int gr = row0 + rg * 8 + j;
        if (gr < N) {
            float v = accv[j] * dinv[gr];
            size_t off = (size_t)gr * D + d;
            hs[off]  = v;
            acc[off] = v;   // self-loop contribution
        }
    }
}

// ---------------------------------------------------------------------------
// acc[dst,:] += hs[src,:]  — 32 threads per edge, float4 gather, scalar atomics
__global__ __launch_bounds__(256) void k_edges(const int* __restrict__ src,
                                               const int* __restrict__ dst,
                                               const float* __restrict__ hs,
                                               float* __restrict__ acc, int E) {
    int idx  = blockIdx.x * blockDim.x + threadIdx.x;
    int e    = idx >> 5;
    int lane = idx & 31;
    if (e >= E) return;
    int s = src[e];
    int t = dst[e];
    float4 v = ((const float4*)(hs + (size_t)s * D))[lane];
    float* ad = acc + (size_t)t * D + lane * 4;
    atomicAdd(ad + 0, v.x);
    atomicAdd(ad + 1, v.y);
    atomicAdd(ad + 2, v.z);
    atomicAdd(ad + 3, v.w);
}

// ---------------------------------------------------------------------------
// out[n,:] = relu(acc[n,:] * dinv[n] + b)   (float4 over N*D)
__global__ void k_final(const float* __restrict__ acc, const float* __restrict__ dinv,
                        const float* __restrict__ b, float* __restrict__ out, int N) {
    int idx = blockIdx.x * blockDim.x + threadIdx.x;   // over N*D/4
    int total = N * (D / 4);
    if (idx >= total) return;
    int n  = idx >> 5;          // D/4 = 32 float4 per row
    int c4 = idx & 31;
    float di = dinv[n];
    float4 a  = ((const float4*)acc)[idx];
    float4 bb = ((const float4*)b)[c4];
    float4 o;
    o.x = fmaxf(fmaf(a.x, di, bb.x), 0.0f);
    o.y = fmaxf(fmaf(a.y, di, bb.y), 0.0f);
    o.z = fmaxf(fmaf(a.z, di, bb.z), 0.0f);
    o.w = fmaxf(fmaf(a.w, di, bb.w), 0.0f);
    ((float4*)out)[idx] = o;
}

// ---------------------------------------------------------------------------
extern "C" void kernel_launch(void* const* d_in, const int* in_sizes, int n_in,
                              void* d_out, int out_size, void* d_ws, size_t ws_size,
                              hipStream_t stream) {
    const float* x  = (const float*)d_in[0];   // [N, D]
    const float* W  = (const float*)d_in[1];   // [D, D]
    const float* b  = (const float*)d_in[2];   // [D]
    const int*   ei = (const int*)d_in[3];     // [2, E]

    const int N = in_sizes[0] / D;             // 50000
    const int E = in_sizes[3] / 2;             // 600000
    const int* src = ei;
    const int* dst = ei + E;

    // workspace layout (floats): dinv[N] | hs[N*D] | acc[N*D]  (~51.6 MB)
    float* ws   = (float*)d_ws;
    float* dinv = ws;
    float* hs   = ws + N;
    float* acc  = hs + (size_t)N * D;

    float* out = (float*)d_out;

    k_deg_init<<<(N + 255) / 256, 256, 0, stream>>>(dinv, N);
    k_deg_count<<<(E + 255) / 256, 256, 0, stream>>>(dst, dinv, E);
    k_dinv<<<(N + 255) / 256, 256, 0, stream>>>(dinv, N);
    k_gemm<<<(N + GEMM_ROWS - 1) / GEMM_ROWS, 256, 0, stream>>>(x, W, dinv, hs, acc, N);
    {
        long long threads = (long long)E * 32;
        int blocks = (int)((threads + 255) / 256);
        k_edges<<<blocks, 256, 0, stream>>>(src, dst, hs, acc, E);
    }
    k_final<<<(N * (D / 4) + 255) / 256, 256, 0, stream>>>(acc, dinv, b, out, N);
}

// Round 2
// 257.633 us; speedup vs baseline: 4.2736x; 4.2736x over previous
//
#include <hip/hip_runtime.h>

#define D 128

// ---------------------------------------------------------------------------
// zero the int histogram + cursor arrays (2N ints)
__global__ void k_zero(int* __restrict__ p, int n) {
    int i = blockIdx.x * blockDim.x + threadIdx.x;
    if (i < n) p[i] = 0;
}

// counts[dst[e]] += 1  (int atomics, L2-friendly)
__global__ void k_hist(const int* __restrict__ dst, int* __restrict__ counts, int E) {
    int i = blockIdx.x * blockDim.x + threadIdx.x;
    if (i < E) atomicAdd(&counts[dst[i]], 1);
}

// dinv[i] = rsqrt(counts[i] + 1)   (+1 = self-loop)
__global__ void k_dinv(const int* __restrict__ counts, float* __restrict__ dinv, int N) {
    int i = blockIdx.x * blockDim.x + threadIdx.x;
    if (i < N) dinv[i] = rsqrtf((float)(counts[i] + 1));
}

// exclusive scan of counts -> offsets[0..N], single block of 1024, chunked
__global__ __launch_bounds__(1024) void k_scan(const int* __restrict__ counts,
                                               int* __restrict__ offsets, int N) {
    __shared__ int tmp[1024];
    __shared__ int carry_s;
    if (threadIdx.x == 0) { carry_s = 0; offsets[0] = 0; }
    __syncthreads();
    for (int base = 0; base < N; base += 1024) {
        int i = base + (int)threadIdx.x;
        int v = (i < N) ? counts[i] : 0;
        tmp[threadIdx.x] = v;
        __syncthreads();
        for (int off = 1; off < 1024; off <<= 1) {
            int t = (threadIdx.x >= off) ? tmp[threadIdx.x - off] : 0;
            __syncthreads();
            tmp[threadIdx.x] += t;
            __syncthreads();
        }
        int carry = carry_s;                 // all threads read old carry
        if (i < N) offsets[i + 1] = carry + tmp[threadIdx.x];
        __syncthreads();
        if (threadIdx.x == 1023) carry_s = carry + tmp[1023];
        __syncthreads();
    }
}

// bucket-scatter edges by dst: sorted_src[offsets[dst] + cursor[dst]++] = src
__global__ void k_scatter(const int* __restrict__ src, const int* __restrict__ dst,
                          const int* __restrict__ offsets, int* __restrict__ cursor,
                          int* __restrict__ sorted_src, int E) {
    int e = blockIdx.x * blockDim.x + threadIdx.x;
    if (e >= E) return;
    int t = dst[e];
    int pos = offsets[t] + atomicAdd(&cursor[t], 1);
    sorted_src[pos] = src[e];
}

// ---------------------------------------------------------------------------
// hs[n,:] = (x[n,:] @ W) * dinv[n]   (source-side normalization folded in)
#define GEMM_ROWS 16
__global__ __launch_bounds__(256) void k_gemm(const float* __restrict__ x,
                                              const float* __restrict__ W,
                                              const float* __restrict__ dinv,
                                              float* __restrict__ hs, int N) {
    __shared__ float xs[GEMM_ROWS][D];
    const int row0 = blockIdx.x * GEMM_ROWS;

    for (int t = threadIdx.x; t < GEMM_ROWS * D; t += 256) {
        int r = t >> 7, c = t & 127;
        int gr = row0 + r;
        xs[r][c] = (gr < N) ? x[(size_t)gr * D + c] : 0.0f;
    }
    __syncthreads();

    const int d  = threadIdx.x & 127;
    const int rg = threadIdx.x >> 7;

    float accv[8];
#pragma unroll
    for (int j = 0; j < 8; ++j) accv[j] = 0.0f;

    for (int k = 0; k < D; ++k) {
        float w = W[(size_t)k * D + d];
#pragma unroll
        for (int j = 0; j < 8; ++j)
            accv[j] = fmaf(xs[rg * 8 + j][k], w, accv[j]);
    }

#pragma unroll
    for (int j = 0; j < 8; ++j) {
        int gr = row0 + rg * 8 + j;
        if (gr < N) hs[(size_t)gr * D + d] = accv[j] * dinv[gr];
    }
}

// ---------------------------------------------------------------------------
// per node v (32 lanes, float4 each): acc = hs[v] + sum_{e in CSR(v)} hs[src_e]
// out[v] = relu(acc * dinv[v] + b). Single coalesced write, no atomics.
__global__ __launch_bounds__(256) void k_aggregate(const float* __restrict__ hs,
                                                   const int* __restrict__ offsets,
                                                   const int* __restrict__ sorted_src,
                                                   const float* __restrict__ dinv,
                                                   const float* __restrict__ b,
                                                   float* __restrict__ out, int N) {
    int idx  = blockIdx.x * blockDim.x + threadIdx.x;
    int v    = idx >> 5;
    int lane = idx & 31;
    if (v >= N) return;

    float4 acc = ((const float4*)(hs + (size_t)v * D))[lane];   // self-loop
    int beg = offsets[v];
    int end = offsets[v + 1];
    for (int i = beg; i < end; ++i) {
        int s = sorted_src[i];                                   // broadcast read
        float4 m = ((const float4*)(hs + (size_t)s * D))[lane];
        acc.x += m.x; acc.y += m.y; acc.z += m.z; acc.w += m.w;
    }

    float di  = dinv[v];
    float4 bb = ((const float4*)b)[lane];
    float4 o;
    o.x = fmaxf(fmaf(acc.x, di, bb.x), 0.0f);
    o.y = fmaxf(fmaf(acc.y, di, bb.y), 0.0f);
    o.z = fmaxf(fmaf(acc.z, di, bb.z), 0.0f);
    o.w = fmaxf(fmaf(acc.w, di, bb.w), 0.0f);
    ((float4*)(out + (size_t)v * D))[lane] = o;
}

// ---------------------------------------------------------------------------
extern "C" void kernel_launch(void* const* d_in, const int* in_sizes, int n_in,
                              void* d_out, int out_size, void* d_ws, size_t ws_size,
                              hipStream_t stream) {
    const float* x  = (const float*)d_in[0];   // [N, D]
    const float* W  = (const float*)d_in[1];   // [D, D]
    const float* b  = (const float*)d_in[2];   // [D]
    const int*   ei = (const int*)d_in[3];     // [2, E]

    const int N = in_sizes[0] / D;             // 50000
    const int E = in_sizes[3] / 2;             // 600000
    const int* src = ei;
    const int* dst = ei + E;

    // workspace layout:
    // ints:   counts[N] | cursor[N] | offsets[N+1] | sorted_src[E]
    // floats: dinv[N] | hs[N*D]
    int*   counts     = (int*)d_ws;
    int*   cursor     = counts + N;
    int*   offsets    = cursor + N;
    int*   sorted_src = offsets + (N + 1);
    float* dinv       = (float*)(sorted_src + E);
    float* hs         = dinv + N;

    float* out = (float*)d_out;

    k_zero<<<(2 * N + 255) / 256, 256, 0, stream>>>(counts, 2 * N);   // counts+cursor
    k_hist<<<(E + 255) / 256, 256, 0, stream>>>(dst, counts, E);
    k_dinv<<<(N + 255) / 256, 256, 0, stream>>>(counts, dinv, N);
    k_scan<<<1, 1024, 0, stream>>>(counts, offsets, N);
    k_scatter<<<(E + 255) / 256, 256, 0, stream>>>(src, dst, offsets, cursor, sorted_src, E);
    k_gemm<<<(N + GEMM_ROWS - 1) / GEMM_ROWS, 256, 0, stream>>>(x, W, dinv, hs, N);
    k_aggregate<<<(N * 32 + 255) / 256, 256, 0, stream>>>(hs, offsets, sorted_src, dinv, b, out, N);
}

// Round 3
// 179.076 us; speedup vs baseline: 6.1483x; 1.4387x over previous
//
#include <hip/hip_runtime.h>

#define D 128
#define SCAN_ELEMS 2048   // 256 threads x 8 elems per scan block

// ---------------------------------------------------------------------------
__global__ void k_zero(int* __restrict__ p, int n) {
    int i = blockIdx.x * blockDim.x + threadIdx.x;
    if (i < n) p[i] = 0;
}

// counts[dst[e]] += 1
__global__ void k_hist(const int* __restrict__ dst, int* __restrict__ counts, int E) {
    int i = blockIdx.x * blockDim.x + threadIdx.x;
    if (i < E) atomicAdd(&counts[dst[i]], 1);
}

// ---------------------------------------------------------------------------
// Hierarchical exclusive scan of counts[0..N-1] -> offsets[0..N].
// Phase 1: per-block (2048 elems) local exclusive scan + block sums.
// Also computes dinv[i] = rsqrt(counts[i]+1) for free.
__global__ __launch_bounds__(256) void k_scan1(const int* __restrict__ counts,
                                               int* __restrict__ offsets,
                                               int* __restrict__ bsum,
                                               float* __restrict__ dinv, int N) {
    __shared__ int ts[256];
    const int Np1 = N + 1;
    const int i0 = blockIdx.x * SCAN_ELEMS + threadIdx.x * 8;

    int v[8];
    int sum = 0;
#pragma unroll
    for (int j = 0; j < 8; ++j) {
        int i = i0 + j;
        int c = (i < N) ? counts[i] : 0;
        if (i < N) dinv[i] = rsqrtf((float)(c + 1));
        v[j] = sum;          // thread-local exclusive prefix
        sum += c;
    }
    ts[threadIdx.x] = sum;
    __syncthreads();
    for (int off = 1; off < 256; off <<= 1) {
        int t = (threadIdx.x >= (unsigned)off) ? ts[threadIdx.x - off] : 0;
        __syncthreads();
        ts[threadIdx.x] += t;
        __syncthreads();
    }
    int excl = ts[threadIdx.x] - sum;   // exclusive prefix of this thread's chunk
#pragma unroll
    for (int j = 0; j < 8; ++j) {
        int i = i0 + j;
        if (i < Np1) offsets[i] = excl + v[j];
    }
    if (threadIdx.x == 255) bsum[blockIdx.x] = ts[255];
}

// Phase 2: exclusive scan of block sums in place (nb <= 64, one wave)
__global__ void k_scan2(int* __restrict__ bsum, int nb) {
    int tid = threadIdx.x;
    int orig = (tid < nb) ? bsum[tid] : 0;
    int v = orig;
    for (int off = 1; off < 64; off <<= 1) {
        int t = __shfl_up(v, off, 64);
        if (tid >= off) v += t;
    }
    if (tid < nb) bsum[tid] = v - orig;
}

// Phase 3: uniform add
__global__ void k_scan3(int* __restrict__ offsets, const int* __restrict__ bsum, int Np1) {
    int i = blockIdx.x * blockDim.x + threadIdx.x;
    if (i < Np1) offsets[i] += bsum[i >> 11];   // i / SCAN_ELEMS
}

// ---------------------------------------------------------------------------
// bucket-scatter edges by dst
__global__ void k_scatter(const int* __restrict__ src, const int* __restrict__ dst,
                          const int* __restrict__ offsets, int* __restrict__ cursor,
                          int* __restrict__ sorted_src, int E) {
    int e = blockIdx.x * blockDim.x + threadIdx.x;
    if (e >= E) return;
    int t = dst[e];
    int pos = offsets[t] + atomicAdd(&cursor[t], 1);
    sorted_src[pos] = src[e];
}

// ---------------------------------------------------------------------------
// hs[n,:] = (x[n,:] @ W) * dinv[n]
#define GEMM_ROWS 16
__global__ __launch_bounds__(256) void k_gemm(const float* __restrict__ x,
                                              const float* __restrict__ W,
                                              const float* __restrict__ dinv,
                                              float* __restrict__ hs, int N) {
    __shared__ float xs[GEMM_ROWS][D];
    const int row0 = blockIdx.x * GEMM_ROWS;

    for (int t = threadIdx.x; t < GEMM_ROWS * D; t += 256) {
        int r = t >> 7, c = t & 127;
        int gr = row0 + r;
        xs[r][c] = (gr < N) ? x[(size_t)gr * D + c] : 0.0f;
    }
    __syncthreads();

    const int d  = threadIdx.x & 127;
    const int rg = threadIdx.x >> 7;

    float accv[8];
#pragma unroll
    for (int j = 0; j < 8; ++j) accv[j] = 0.0f;

    for (int k = 0; k < D; ++k) {
        float w = W[(size_t)k * D + d];
#pragma unroll
        for (int j = 0; j < 8; ++j)
            accv[j] = fmaf(xs[rg * 8 + j][k], w, accv[j]);
    }

#pragma unroll
    for (int j = 0; j < 8; ++j) {
        int gr = row0 + rg * 8 + j;
        if (gr < N) hs[(size_t)gr * D + d] = accv[j] * dinv[gr];
    }
}

// ---------------------------------------------------------------------------
// per node v (32 lanes, float4 each): acc = hs[v] + sum_{CSR(v)} hs[src]
// out[v] = relu(acc * dinv[v] + b)
__global__ __launch_bounds__(256) void k_aggregate(const float* __restrict__ hs,
                                                   const int* __restrict__ offsets,
                                                   const int* __restrict__ sorted_src,
                                                   const float* __restrict__ dinv,
                                                   const float* __restrict__ b,
                                                   float* __restrict__ out, int N) {
    int idx  = blockIdx.x * blockDim.x + threadIdx.x;
    int v    = idx >> 5;
    int lane = idx & 31;
    if (v >= N) return;

    float4 acc = ((const float4*)(hs + (size_t)v * D))[lane];   // self-loop
    int beg = offsets[v];
    int end = offsets[v + 1];
    for (int i = beg; i < end; ++i) {
        int s = sorted_src[i];
        float4 m = ((const float4*)(hs + (size_t)s * D))[lane];
        acc.x += m.x; acc.y += m.y; acc.z += m.z; acc.w += m.w;
    }

    float di  = dinv[v];
    float4 bb = ((const float4*)b)[lane];
    float4 o;
    o.x = fmaxf(fmaf(acc.x, di, bb.x), 0.0f);
    o.y = fmaxf(fmaf(acc.y, di, bb.y), 0.0f);
    o.z = fmaxf(fmaf(acc.z, di, bb.z), 0.0f);
    o.w = fmaxf(fmaf(acc.w, di, bb.w), 0.0f);
    ((float4*)(out + (size_t)v * D))[lane] = o;
}

// ---------------------------------------------------------------------------
extern "C" void kernel_launch(void* const* d_in, const int* in_sizes, int n_in,
                              void* d_out, int out_size, void* d_ws, size_t ws_size,
                              hipStream_t stream) {
    const float* x  = (const float*)d_in[0];   // [N, D]
    const float* W  = (const float*)d_in[1];   // [D, D]
    const float* b  = (const float*)d_in[2];   // [D]
    const int*   ei = (const int*)d_in[3];     // [2, E]

    const int N = in_sizes[0] / D;             // 50000
    const int E = in_sizes[3] / 2;             // 600000
    const int* src = ei;
    const int* dst = ei + E;

    // workspace layout:
    // ints:   counts[N] | cursor[N] | offsets[N+1] | bsum[64] | sorted_src[E]
    // floats: dinv[N] | hs[N*D]
    int*   counts     = (int*)d_ws;
    int*   cursor     = counts + N;
    int*   offsets    = cursor + N;
    int*   bsum       = offsets + (N + 1);
    int*   sorted_src = bsum + 64;
    float* dinv       = (float*)(sorted_src + E);
    float* hs         = dinv + N;

    float* out = (float*)d_out;

    const int Np1 = N + 1;
    const int nb1 = (Np1 + SCAN_ELEMS - 1) / SCAN_ELEMS;   // 25 blocks

    k_zero<<<(2 * N + 255) / 256, 256, 0, stream>>>(counts, 2 * N);
    k_hist<<<(E + 255) / 256, 256, 0, stream>>>(dst, counts, E);
    k_scan1<<<nb1, 256, 0, stream>>>(counts, offsets, bsum, dinv, N);
    k_scan2<<<1, 64, 0, stream>>>(bsum, nb1);
    k_scan3<<<(Np1 + 255) / 256, 256, 0, stream>>>(offsets, bsum, Np1);
    k_scatter<<<(E + 255) / 256, 256, 0, stream>>>(src, dst, offsets, cursor, sorted_src, E);
    k_gemm<<<(N + GEMM_ROWS - 1) / GEMM_ROWS, 256, 0, stream>>>(x, W, dinv, hs, N);
    k_aggregate<<<(N * 32 + 255) / 256, 256, 0, stream>>>(hs, offsets, sorted_src, dinv, b, out, N);
}

// Round 4
// 133.633 us; speedup vs baseline: 8.2391x; 1.3401x over previous
//
#include <hip/hip_runtime.h>

#define D 128
#define SCAN_ELEMS 2048   // 256 threads x 8 elems per scan block

typedef __attribute__((ext_vector_type(8))) short bf16x8;
typedef __attribute__((ext_vector_type(4))) float f32x4;
typedef __attribute__((ext_vector_type(8))) unsigned short us8;

static __device__ __forceinline__ float bf2f(unsigned short u) {
    union { unsigned int i; float f; } c; c.i = ((unsigned int)u) << 16; return c.f;
}
static __device__ __forceinline__ unsigned short f2bf(float f) {
    union { float f; unsigned int i; } c; c.f = f;
    unsigned int r = c.i + 0x7FFFu + ((c.i >> 16) & 1u);   // RTN-even
    return (unsigned short)(r >> 16);
}

// ---------------------------------------------------------------------------
__global__ void k_zero(int* __restrict__ p, int n) {
    int i = blockIdx.x * blockDim.x + threadIdx.x;
    if (i < n) p[i] = 0;
}

__global__ void k_hist(const int* __restrict__ dst, int* __restrict__ counts, int E) {
    int i = blockIdx.x * blockDim.x + threadIdx.x;
    if (i < E) atomicAdd(&counts[dst[i]], 1);
}

// ---------------------------------------------------------------------------
// Phase 1: per-block local exclusive scan + block sums; dinv = rsqrt(count+1).
__global__ __launch_bounds__(256) void k_scan1(const int* __restrict__ counts,
                                               int* __restrict__ offsets,
                                               int* __restrict__ bsum,
                                               float* __restrict__ dinv, int N) {
    __shared__ int ts[256];
    const int Np1 = N + 1;
    const int i0 = blockIdx.x * SCAN_ELEMS + threadIdx.x * 8;

    int v[8];
    int sum = 0;
#pragma unroll
    for (int j = 0; j < 8; ++j) {
        int i = i0 + j;
        int c = (i < N) ? counts[i] : 0;
        if (i < N) dinv[i] = rsqrtf((float)(c + 1));
        v[j] = sum;
        sum += c;
    }
    ts[threadIdx.x] = sum;
    __syncthreads();
    for (int off = 1; off < 256; off <<= 1) {
        int t = (threadIdx.x >= (unsigned)off) ? ts[threadIdx.x - off] : 0;
        __syncthreads();
        ts[threadIdx.x] += t;
        __syncthreads();
    }
    int excl = ts[threadIdx.x] - sum;
#pragma unroll
    for (int j = 0; j < 8; ++j) {
        int i = i0 + j;
        if (i < Np1) offsets[i] = excl + v[j];
    }
    if (threadIdx.x == 255) bsum[blockIdx.x] = ts[255];
}

// Phase 2: exclusive scan of block sums (nb <= 64, one wave)
__global__ void k_scan2(int* __restrict__ bsum, int nb) {
    int tid = threadIdx.x;
    int orig = (tid < nb) ? bsum[tid] : 0;
    int v = orig;
    for (int off = 1; off < 64; off <<= 1) {
        int t = __shfl_up(v, off, 64);
        if (tid >= off) v += t;
    }
    if (tid < nb) bsum[tid] = v - orig;
}

// Phase 3: uniform add; also seed cursor = offsets for the scatter pass
__global__ void k_scan3(int* __restrict__ offsets, int* __restrict__ cursor,
                        const int* __restrict__ bsum, int N) {
    int i = blockIdx.x * blockDim.x + threadIdx.x;
    if (i <= N) {
        int v = offsets[i] + bsum[i >> 11];   // i / SCAN_ELEMS
        offsets[i] = v;
        if (i < N) cursor[i] = v;
    }
}

// ---------------------------------------------------------------------------
// bucket-scatter edges by dst (cursor pre-seeded with offsets)
__global__ void k_scatter(const int* __restrict__ src, const int* __restrict__ dst,
                          int* __restrict__ cursor, int* __restrict__ sorted_src, int E) {
    int e = blockIdx.x * blockDim.x + threadIdx.x;
    if (e >= E) return;
    int pos = atomicAdd(&cursor[dst[e]], 1);
    sorted_src[pos] = src[e];
}

// ---------------------------------------------------------------------------
// Wt[c][k] = bf16(W[k][c])  (one-time 64 KB transpose+convert)
__global__ void k_wprep(const float* __restrict__ W, unsigned short* __restrict__ Wt) {
    int t = blockIdx.x * blockDim.x + threadIdx.x;   // 16384
    int k = t >> 7, c = t & 127;
    Wt[c * D + k] = f2bf(W[k * D + c]);
}

// ---------------------------------------------------------------------------
// hs[n,:] = bf16( (x[n,:] @ W) * dinv[n] )  via 16x16x32 bf16 MFMA.
// Block = 256 threads = 4 waves; wave w owns rows m0 = blk*64 + w*16 (x full K).
// A-frag: x[m0+(l&15)][kk*32 + (l>>4)*8 + 0..7] (f32 -> bf16 in regs)
// B-frag: Wt[nt*16+(l&15)][same k range] (contiguous 16 B)
// D: col = lane&15, row = 4*(lane>>4)+j  (m89-verified layout)
__global__ __launch_bounds__(256) void k_gemm_mfma(const float* __restrict__ x,
                                                   const unsigned short* __restrict__ Wt,
                                                   const float* __restrict__ dinv,
                                                   unsigned short* __restrict__ hs, int N) {
    const int wave = threadIdx.x >> 6;
    const int l    = threadIdx.x & 63;
    const int m0   = blockIdx.x * 64 + wave * 16;
    const int lr   = l & 15;
    const int kg   = l >> 4;
    const int row_a = m0 + lr;

    f32x4 acc[8];
#pragma unroll
    for (int t = 0; t < 8; ++t) acc[t] = (f32x4){0.f, 0.f, 0.f, 0.f};

#pragma unroll
    for (int kk = 0; kk < 4; ++kk) {
        const int kbase = kk * 32 + kg * 8;
        bf16x8 afrag;
        if (row_a < N) {
            const float* xp = x + (size_t)row_a * D + kbase;
            f32x4 x0 = *(const f32x4*)xp;
            f32x4 x1 = *(const f32x4*)(xp + 4);
#pragma unroll
            for (int j = 0; j < 4; ++j) afrag[j] = (short)f2bf(x0[j]);
#pragma unroll
            for (int j = 0; j < 4; ++j) afrag[4 + j] = (short)f2bf(x1[j]);
        } else {
#pragma unroll
            for (int j = 0; j < 8; ++j) afrag[j] = 0;
        }
#pragma unroll
        for (int nt = 0; nt < 8; ++nt) {
            bf16x8 bfrag = *(const bf16x8*)(Wt + (size_t)(nt * 16 + lr) * D + kbase);
            acc[nt] = __builtin_amdgcn_mfma_f32_16x16x32_bf16(afrag, bfrag, acc[nt], 0, 0, 0);
        }
    }

#pragma unroll
    for (int j = 0; j < 4; ++j) {
        int row = m0 + kg * 4 + j;
        if (row < N) {
            float di = dinv[row];
#pragma unroll
            for (int nt = 0; nt < 8; ++nt)
                hs[(size_t)row * D + nt * 16 + lr] = f2bf(acc[nt][j] * di);
        }
    }
}

// ---------------------------------------------------------------------------
// per node v (16 lanes x ushort8): acc = hs[v] + sum_{CSR(v)} hs[src]  (f32 acc)
// out[v] = relu(acc * dinv[v] + b)
__global__ __launch_bounds__(256) void k_aggregate(const unsigned short* __restrict__ hs,
                                                   const int* __restrict__ offsets,
                                                   const int* __restrict__ sorted_src,
                                                   const float* __restrict__ dinv,
                                                   const float* __restrict__ b,
                                                   float* __restrict__ out, int N) {
    int idx  = blockIdx.x * blockDim.x + threadIdx.x;
    int v    = idx >> 4;
    int lane = idx & 15;
    if (v >= N) return;

    float acc[8];
    {
        us8 h = *(const us8*)(hs + (size_t)v * D + lane * 8);
#pragma unroll
        for (int j = 0; j < 8; ++j) acc[j] = bf2f(h[j]);
    }

    int i   = offsets[v];
    int end = offsets[v + 1];
    for (; i + 4 <= end; i += 4) {
        int s0 = sorted_src[i + 0];
        int s1 = sorted_src[i + 1];
        int s2 = sorted_src[i + 2];
        int s3 = sorted_src[i + 3];
        us8 m0 = *(const us8*)(hs + (size_t)s0 * D + lane * 8);
        us8 m1 = *(const us8*)(hs + (size_t)s1 * D + lane * 8);
        us8 m2 = *(const us8*)(hs + (size_t)s2 * D + lane * 8);
        us8 m3 = *(const us8*)(hs + (size_t)s3 * D + lane * 8);
#pragma unroll
        for (int j = 0; j < 8; ++j)
            acc[j] += (bf2f(m0[j]) + bf2f(m1[j])) + (bf2f(m2[j]) + bf2f(m3[j]));
    }
    for (; i < end; ++i) {
        int s = sorted_src[i];
        us8 m = *(const us8*)(hs + (size_t)s * D + lane * 8);
#pragma unroll
        for (int j = 0; j < 8; ++j) acc[j] += bf2f(m[j]);
    }

    float di = dinv[v];
    f32x4 b0 = *(const f32x4*)(b + lane * 8);
    f32x4 b1 = *(const f32x4*)(b + lane * 8 + 4);
    f32x4 o0, o1;
#pragma unroll
    for (int j = 0; j < 4; ++j) {
        o0[j] = fmaxf(fmaf(acc[j],     di, b0[j]), 0.0f);
        o1[j] = fmaxf(fmaf(acc[4 + j], di, b1[j]), 0.0f);
    }
    float* op = out + (size_t)v * D + lane * 8;
    *(f32x4*)op       = o0;
    *(f32x4*)(op + 4) = o1;
}

// ---------------------------------------------------------------------------
static inline char* align_up(char* p, size_t a) {
    return (char*)(((uintptr_t)p + a - 1) & ~(uintptr_t)(a - 1));
}

extern "C" void kernel_launch(void* const* d_in, const int* in_sizes, int n_in,
                              void* d_out, int out_size, void* d_ws, size_t ws_size,
                              hipStream_t stream) {
    const float* x  = (const float*)d_in[0];   // [N, D]
    const float* W  = (const float*)d_in[1];   // [D, D]
    const float* b  = (const float*)d_in[2];   // [D]
    const int*   ei = (const int*)d_in[3];     // [2, E]

    const int N = in_sizes[0] / D;             // 50000
    const int E = in_sizes[3] / 2;             // 600000
    const int* src = ei;
    const int* dst = ei + E;

    // workspace layout (64 B aligned sections):
    // counts[N] cursor[N] offsets[N+1] bsum[64] sorted_src[E] (int)
    // dinv[N] (f32) | Wt[D*D] (bf16) | hs[N*D] (bf16)
    char* p = (char*)d_ws;
    int* counts      = (int*)p;              p = align_up(p + sizeof(int) * N, 64);
    int* cursor      = (int*)p;              p = align_up(p + sizeof(int) * N, 64);
    int* offsets     = (int*)p;              p = align_up(p + sizeof(int) * (N + 1), 64);
    int* bsum        = (int*)p;              p = align_up(p + sizeof(int) * 64, 64);
    int* sorted_src  = (int*)p;              p = align_up(p + sizeof(int) * E, 64);
    float* dinv      = (float*)p;            p = align_up(p + sizeof(float) * N, 64);
    unsigned short* Wt = (unsigned short*)p; p = align_up(p + sizeof(short) * D * D, 64);
    unsigned short* hs = (unsigned short*)p;

    float* out = (float*)d_out;

    const int Np1 = N + 1;
    const int nb1 = (Np1 + SCAN_ELEMS - 1) / SCAN_ELEMS;   // 25

    k_zero<<<(N + 255) / 256, 256, 0, stream>>>(counts, N);
    k_hist<<<(E + 255) / 256, 256, 0, stream>>>(dst, counts, E);
    k_scan1<<<nb1, 256, 0, stream>>>(counts, offsets, bsum, dinv, N);
    k_scan2<<<1, 64, 0, stream>>>(bsum, nb1);
    k_scan3<<<(Np1 + 255) / 256, 256, 0, stream>>>(offsets, cursor, bsum, N);
    k_scatter<<<(E + 255) / 256, 256, 0, stream>>>(src, dst, cursor, sorted_src, E);
    k_wprep<<<(D * D) / 256, 256, 0, stream>>>(W, Wt);
    k_gemm_mfma<<<(N + 63) / 64, 256, 0, stream>>>(x, Wt, dinv, hs, N);
    k_aggregate<<<(N * 16 + 255) / 256, 256, 0, stream>>>(hs, offsets, sorted_src, dinv, b, out, N);
}

// Round 8
// 115.861 us; speedup vs baseline: 9.5029x; 1.1534x over previous
//
#include <hip/hip_runtime.h>

#define D 128
#define SCAN_ELEMS 2048  // 256 threads x 8 elems per scan chunk

typedef __attribute__((ext_vector_type(8))) short bf16x8;
typedef __attribute__((ext_vector_type(4))) float f32x4;
typedef __attribute__((ext_vector_type(8))) unsigned short us8;
typedef __attribute__((ext_vector_type(4))) int i32x4;

static __device__ __forceinline__ float bf2f(unsigned short u) {
    union { unsigned int i; float f; } c; c.i = ((unsigned int)u) << 16; return c.f;
}
static __device__ __forceinline__ unsigned short f2bf(float f) {
    union { float f; unsigned int i; } c; c.f = f;
    unsigned int r = c.i + 0x7FFFu + ((c.i >> 16) & 1u);   // RTN-even
    return (unsigned short)(r >> 16);
}

// ---------------------------------------------------------------------------
// counts[dst[e]]++  (4 edges per thread via int4)
__global__ void k_hist(const int* __restrict__ dst, int* __restrict__ counts, int E) {
    int i = (blockIdx.x * blockDim.x + threadIdx.x) * 4;
    if (i + 4 <= E) {
        i32x4 d = *(const i32x4*)(dst + i);
        atomicAdd(&counts[d.x], 1);
        atomicAdd(&counts[d.y], 1);
        atomicAdd(&counts[d.z], 1);
        atomicAdd(&counts[d.w], 1);
    } else {
        for (; i < E; ++i) atomicAdd(&counts[dst[i]], 1);
    }
}

// ---------------------------------------------------------------------------
// Phase 1 of scan: per-block (2048 elems) local exclusive scan + block sums.
__global__ __launch_bounds__(256) void k_scan1(const int* __restrict__ counts,
                                               int* __restrict__ offsets,
                                               int* __restrict__ bsum, int N) {
    __shared__ int ts[256];
    const int i0 = blockIdx.x * SCAN_ELEMS + threadIdx.x * 8;
    int v[8];
    int sum = 0;
#pragma unroll
    for (int j = 0; j < 8; ++j) {
        int i = i0 + j;
        int c = (i < N) ? counts[i] : 0;
        v[j] = sum;
        sum += c;
    }
    ts[threadIdx.x] = sum;
    __syncthreads();
    for (int off = 1; off < 256; off <<= 1) {
        int t = (threadIdx.x >= (unsigned)off) ? ts[threadIdx.x - off] : 0;
        __syncthreads();
        ts[threadIdx.x] += t;
        __syncthreads();
    }
    int excl = ts[threadIdx.x] - sum;
#pragma unroll
    for (int j = 0; j < 8; ++j) {
        int i = i0 + j;
        if (i <= N) offsets[i] = excl + v[j];
    }
    if (threadIdx.x == 255) bsum[blockIdx.x] = ts[255];
}

// Phase 2: wave 0 scans the nb1 (<=64) block sums with ALL 64 lanes active,
// stages the exclusive prefix in LDS; all threads then read it from LDS.
// (No cross-lane op under divergence — the R6/R7 bug.)
__global__ __launch_bounds__(256) void k_scan3(int* __restrict__ offsets,
                                               int* __restrict__ cursor,
                                               const int* __restrict__ bsum,
                                               int N, int nb1) {
    __shared__ int pre[64];
    if (threadIdx.x < 64) {
        const int lane = (int)threadIdx.x;
        int bv = (lane < nb1) ? bsum[lane] : 0;
        int inc = bv;
        for (int off = 1; off < 64; off <<= 1) {
            int t = __shfl_up(inc, off, 64);
            if (lane >= off) inc += t;
        }
        pre[lane] = inc - bv;
    }
    __syncthreads();

    int i = blockIdx.x * blockDim.x + threadIdx.x;
    if (i <= N) {
        int add = pre[(i >> 11) & 63];       // i / SCAN_ELEMS
        int v = offsets[i] + add;
        offsets[i] = v;
        if (i < N) cursor[i] = v;
    }
}

// ---------------------------------------------------------------------------
// bucket-scatter edges by dst (cursor pre-seeded with offsets); int4 loads
__global__ void k_scatter(const int* __restrict__ src, const int* __restrict__ dst,
                          int* __restrict__ cursor, int* __restrict__ sorted_src, int E) {
    int e = (blockIdx.x * blockDim.x + threadIdx.x) * 4;
    if (e + 4 <= E) {
        i32x4 d = *(const i32x4*)(dst + e);
        i32x4 s = *(const i32x4*)(src + e);
        sorted_src[atomicAdd(&cursor[d.x], 1)] = s.x;
        sorted_src[atomicAdd(&cursor[d.y], 1)] = s.y;
        sorted_src[atomicAdd(&cursor[d.z], 1)] = s.z;
        sorted_src[atomicAdd(&cursor[d.w], 1)] = s.w;
    } else {
        for (; e < E; ++e)
            sorted_src[atomicAdd(&cursor[dst[e]], 1)] = src[e];
    }
}

// ---------------------------------------------------------------------------
// hs[n,:] = bf16( (x[n,:] @ W) * rsqrt(deg[n]) ) via 16x16x32 bf16 MFMA.
// W converted+transposed into LDS per block (34 KB, rows padded +8 shorts).
// Block = 4 waves; wave w owns rows m0 = blk*64 + w*16 (full K).
// D-frag layout: col = lane&15, row = 4*(lane>>4)+j  (m89-verified).
__global__ __launch_bounds__(256) void k_gemm_mfma(const float* __restrict__ x,
                                                   const float* __restrict__ W,
                                                   const int* __restrict__ counts,
                                                   unsigned short* __restrict__ hs, int N) {
    __shared__ unsigned short wlds[D][D + 8];
    for (int t = threadIdx.x; t < D * D; t += 256) {
        int k = t >> 7, c = t & 127;
        wlds[c][k] = f2bf(W[t]);            // wlds[col][k] = W[k][col]
    }
    __syncthreads();

    const int wave = threadIdx.x >> 6;
    const int l    = threadIdx.x & 63;
    const int m0   = blockIdx.x * 64 + wave * 16;
    const int lr   = l & 15;
    const int kg   = l >> 4;
    const int row_a = m0 + lr;

    f32x4 acc[8];
#pragma unroll
    for (int t = 0; t < 8; ++t) acc[t] = (f32x4){0.f, 0.f, 0.f, 0.f};

#pragma unroll
    for (int kk = 0; kk < 4; ++kk) {
        const int kbase = kk * 32 + kg * 8;
        bf16x8 afrag;
        if (row_a < N) {
            const float* xp = x + (size_t)row_a * D + kbase;
            f32x4 x0 = *(const f32x4*)xp;
            f32x4 x1 = *(const f32x4*)(xp + 4);
#pragma unroll
            for (int j = 0; j < 4; ++j) afrag[j] = (short)f2bf(x0[j]);
#pragma unroll
            for (int j = 0; j < 4; ++j) afrag[4 + j] = (short)f2bf(x1[j]);
        } else {
#pragma unroll
            for (int j = 0; j < 8; ++j) afrag[j] = 0;
        }
#pragma unroll
        for (int nt = 0; nt < 8; ++nt) {
            bf16x8 bfrag = *(const bf16x8*)&wlds[nt * 16 + lr][kbase];
            acc[nt] = __builtin_amdgcn_mfma_f32_16x16x32_bf16(afrag, bfrag, acc[nt], 0, 0, 0);
        }
    }

#pragma unroll
    for (int j = 0; j < 4; ++j) {
        int row = m0 + kg * 4 + j;
        if (row < N) {
            float di = rsqrtf((float)(counts[row] + 1));
#pragma unroll
            for (int nt = 0; nt < 8; ++nt)
                hs[(size_t)row * D + nt * 16 + lr] = f2bf(acc[nt][j] * di);
        }
    }
}

// ---------------------------------------------------------------------------
// per node v (16 lanes x ushort8): acc = hs[v] + sum_{CSR(v)} hs[src]  (f32)
// out[v] = relu(acc * rsqrt(deg[v]) + b)
__global__ __launch_bounds__(256) void k_aggregate(const unsigned short* __restrict__ hs,
                                                   const int* __restrict__ offsets,
                                                   const int* __restrict__ sorted_src,
                                                   const int* __restrict__ counts,
                                                   const float* __restrict__ b,
                                                   float* __restrict__ out, int N) {
    int idx  = blockIdx.x * blockDim.x + threadIdx.x;
    int v    = idx >> 4;
    int lane = idx & 15;
    if (v >= N) return;

    float acc[8];
    {
        us8 h = *(const us8*)(hs + (size_t)v * D + lane * 8);
#pragma unroll
        for (int j = 0; j < 8; ++j) acc[j] = bf2f(h[j]);
    }

    int i   = offsets[v];
    int end = offsets[v + 1];
    for (; i + 4 <= end; i += 4) {
        int s0 = sorted_src[i + 0];
        int s1 = sorted_src[i + 1];
        int s2 = sorted_src[i + 2];
        int s3 = sorted_src[i + 3];
        us8 m0 = *(const us8*)(hs + (size_t)s0 * D + lane * 8);
        us8 m1 = *(const us8*)(hs + (size_t)s1 * D + lane * 8);
        us8 m2 = *(const us8*)(hs + (size_t)s2 * D + lane * 8);
        us8 m3 = *(const us8*)(hs + (size_t)s3 * D + lane * 8);
#pragma unroll
        for (int j = 0; j < 8; ++j)
            acc[j] += (bf2f(m0[j]) + bf2f(m1[j])) + (bf2f(m2[j]) + bf2f(m3[j]));
    }
    for (; i < end; ++i) {
        int s = sorted_src[i];
        us8 m = *(const us8*)(hs + (size_t)s * D + lane * 8);
#pragma unroll
        for (int j = 0; j < 8; ++j) acc[j] += bf2f(m[j]);
    }

    float di = rsqrtf((float)(counts[v] + 1));
    f32x4 b0 = *(const f32x4*)(b + lane * 8);
    f32x4 b1 = *(const f32x4*)(b + lane * 8 + 4);
    f32x4 o0, o1;
#pragma unroll
    for (int j = 0; j < 4; ++j) {
        o0[j] = fmaxf(fmaf(acc[j],     di, b0[j]), 0.0f);
        o1[j] = fmaxf(fmaf(acc[4 + j], di, b1[j]), 0.0f);
    }
    float* op = out + (size_t)v * D + lane * 8;
    *(f32x4*)op       = o0;
    *(f32x4*)(op + 4) = o1;
}

// ---------------------------------------------------------------------------
static inline char* align_up(char* p, size_t a) {
    return (char*)(((uintptr_t)p + a - 1) & ~(uintptr_t)(a - 1));
}

extern "C" void kernel_launch(void* const* d_in, const int* in_sizes, int n_in,
                              void* d_out, int out_size, void* d_ws, size_t ws_size,
                              hipStream_t stream) {
    const float* x  = (const float*)d_in[0];   // [N, D]
    const float* W  = (const float*)d_in[1];   // [D, D]
    const float* b  = (const float*)d_in[2];   // [D]
    const int*   ei = (const int*)d_in[3];     // [2, E]

    const int N = in_sizes[0] / D;             // 50000
    const int E = in_sizes[3] / 2;             // 600000
    const int* src = ei;
    const int* dst = ei + E;

    // workspace layout (64 B aligned sections):
    // counts[N] cursor[N] offsets[N+1] bsum[64] sorted_src[E] (int) | hs[N*D] bf16
    char* p = (char*)d_ws;
    int* counts        = (int*)p;              p = align_up(p + sizeof(int) * N, 64);
    int* cursor        = (int*)p;              p = align_up(p + sizeof(int) * N, 64);
    int* offsets       = (int*)p;              p = align_up(p + sizeof(int) * (N + 1), 64);
    int* bsum          = (int*)p;              p = align_up(p + sizeof(int) * 64, 64);
    int* sorted_src    = (int*)p;              p = align_up(p + sizeof(int) * E, 64);
    unsigned short* hs = (unsigned short*)p;

    float* out = (float*)d_out;

    const int nb1 = (N + 1 + SCAN_ELEMS - 1) / SCAN_ELEMS;   // 25 (<= 64 required)

    hipMemsetAsync(counts, 0, sizeof(int) * N, stream);
    k_hist<<<(E / 4 + 255) / 256, 256, 0, stream>>>(dst, counts, E);
    k_scan1<<<nb1, 256, 0, stream>>>(counts, offsets, bsum, N);
    k_scan3<<<(N + 256) / 256, 256, 0, stream>>>(offsets, cursor, bsum, N, nb1);
    k_scatter<<<(E / 4 + 255) / 256, 256, 0, stream>>>(src, dst, cursor, sorted_src, E);
    k_gemm_mfma<<<(N + 63) / 64, 256, 0, stream>>>(x, W, counts, hs, N);
    k_aggregate<<<(N * 16 + 255) / 256, 256, 0, stream>>>(hs, offsets, sorted_src, counts, b, out, N);
}

// Round 9
// 114.562 us; speedup vs baseline: 9.6106x; 1.0113x over previous
//
#include <hip/hip_runtime.h>

#define D 128
#define SCAN_ELEMS 2048  // 256 threads x 8 elems per scan chunk

typedef __attribute__((ext_vector_type(8))) short bf16x8;
typedef __attribute__((ext_vector_type(4))) float f32x4;
typedef __attribute__((ext_vector_type(8))) unsigned short us8;
typedef __attribute__((ext_vector_type(4))) int i32x4;

static __device__ __forceinline__ float bf2f(unsigned short u) {
    union { unsigned int i; float f; } c; c.i = ((unsigned int)u) << 16; return c.f;
}
static __device__ __forceinline__ unsigned short f2bf(float f) {
    union { float f; unsigned int i; } c; c.f = f;
    unsigned int r = c.i + 0x7FFFu + ((c.i >> 16) & 1u);   // RTN-even
    return (unsigned short)(r >> 16);
}

// ---------------------------------------------------------------------------
// Fused kernel: blocks [0, gemm_blks) do the MFMA GEMM (hs = bf16(x @ W),
// UNSCALED — dinv applied later per-edge); blocks [gemm_blks, ...) do the
// degree histogram. The two roles are fully independent (GEMM no longer
// reads counts), so no sync is needed — hist's atomic latency hides under
// the GEMM's MFMA work.
__global__ __launch_bounds__(256) void k_gemm_hist(const float* __restrict__ x,
                                                   const float* __restrict__ W,
                                                   const int* __restrict__ dst,
                                                   int* __restrict__ counts,
                                                   unsigned short* __restrict__ hs,
                                                   int N, int E, int gemm_blks) {
    if ((int)blockIdx.x >= gemm_blks) {
        // ---- histogram role: 4 edges per thread via int4 ----
        int i = (((int)blockIdx.x - gemm_blks) * 256 + (int)threadIdx.x) * 4;
        if (i + 4 <= E) {
            i32x4 d = *(const i32x4*)(dst + i);
            atomicAdd(&counts[d.x], 1);
            atomicAdd(&counts[d.y], 1);
            atomicAdd(&counts[d.z], 1);
            atomicAdd(&counts[d.w], 1);
        } else {
            for (; i < E; ++i) atomicAdd(&counts[dst[i]], 1);
        }
        return;
    }

    // ---- GEMM role: hs[n,:] = bf16(x[n,:] @ W) via 16x16x32 bf16 MFMA ----
    // W converted+transposed into LDS (34 KB, rows padded +8 shorts).
    __shared__ unsigned short wlds[D][D + 8];
    for (int t = threadIdx.x; t < D * D; t += 256) {
        int k = t >> 7, c = t & 127;
        wlds[c][k] = f2bf(W[t]);            // wlds[col][k] = W[k][col]
    }
    __syncthreads();

    const int wave = threadIdx.x >> 6;
    const int l    = threadIdx.x & 63;
    const int m0   = (int)blockIdx.x * 64 + wave * 16;
    const int lr   = l & 15;
    const int kg   = l >> 4;
    const int row_a = m0 + lr;

    f32x4 acc[8];
#pragma unroll
    for (int t = 0; t < 8; ++t) acc[t] = (f32x4){0.f, 0.f, 0.f, 0.f};

#pragma unroll
    for (int kk = 0; kk < 4; ++kk) {
        const int kbase = kk * 32 + kg * 8;
        bf16x8 afrag;
        if (row_a < N) {
            const float* xp = x + (size_t)row_a * D + kbase;
            f32x4 x0 = *(const f32x4*)xp;
            f32x4 x1 = *(const f32x4*)(xp + 4);
#pragma unroll
            for (int j = 0; j < 4; ++j) afrag[j] = (short)f2bf(x0[j]);
#pragma unroll
            for (int j = 0; j < 4; ++j) afrag[4 + j] = (short)f2bf(x1[j]);
        } else {
#pragma unroll
            for (int j = 0; j < 8; ++j) afrag[j] = 0;
        }
#pragma unroll
        for (int nt = 0; nt < 8; ++nt) {
            bf16x8 bfrag = *(const bf16x8*)&wlds[nt * 16 + lr][kbase];
            acc[nt] = __builtin_amdgcn_mfma_f32_16x16x32_bf16(afrag, bfrag, acc[nt], 0, 0, 0);
        }
    }

    // D-frag layout: col = lane&15, row = 4*(lane>>4)+j  (m89-verified)
#pragma unroll
    for (int j = 0; j < 4; ++j) {
        int row = m0 + kg * 4 + j;
        if (row < N) {
#pragma unroll
            for (int nt = 0; nt < 8; ++nt)
                hs[(size_t)row * D + nt * 16 + lr] = f2bf(acc[nt][j]);
        }
    }
}

// ---------------------------------------------------------------------------
// Scan phase 1: per-block (2048 elems) local exclusive scan of counts into
// offsets (chunk-local values!), chunk sums into bsum; dinv computed free.
__global__ __launch_bounds__(256) void k_scan1(const int* __restrict__ counts,
                                               int* __restrict__ offsets,
                                               int* __restrict__ bsum,
                                               float* __restrict__ dinv, int N) {
    __shared__ int ts[256];
    const int i0 = blockIdx.x * SCAN_ELEMS + threadIdx.x * 8;
    int v[8];
    int sum = 0;
#pragma unroll
    for (int j = 0; j < 8; ++j) {
        int i = i0 + j;
        int c = (i < N) ? counts[i] : 0;
        if (i < N) dinv[i] = rsqrtf((float)(c + 1));
        v[j] = sum;
        sum += c;
    }
    ts[threadIdx.x] = sum;
    __syncthreads();
    for (int off = 1; off < 256; off <<= 1) {
        int t = (threadIdx.x >= (unsigned)off) ? ts[threadIdx.x - off] : 0;
        __syncthreads();
        ts[threadIdx.x] += t;
        __syncthreads();
    }
    int excl = ts[threadIdx.x] - sum;
#pragma unroll
    for (int j = 0; j < 8; ++j) {
        int i = i0 + j;
        if (i <= N) offsets[i] = excl + v[j];
    }
    if (threadIdx.x == 255) bsum[blockIdx.x] = ts[255];
}

// Helper: wave 0 (all 64 lanes active) scans bsum -> exclusive prefix in LDS.
static __device__ __forceinline__ void scan_bsum_to_lds(const int* __restrict__ bsum,
                                                        int nb1, int* pre) {
    if (threadIdx.x < 64) {
        const int lane = (int)threadIdx.x;
        int bv = (lane < nb1) ? bsum[lane] : 0;
        int inc = bv;
        for (int off = 1; off < 64; off <<= 1) {
            int t = __shfl_up(inc, off, 64);
            if (lane >= off) inc += t;
        }
        pre[lane] = inc - bv;
    }
    __syncthreads();
}

// ---------------------------------------------------------------------------
// bucket-scatter edges by dst. Global position = chunk-local offsets[t]
// + pre[chunk(t)] + cursor0[t]++ (cursor0 zeroed by the memset).
__global__ __launch_bounds__(256) void k_scatter(const int* __restrict__ src,
                                                 const int* __restrict__ dst,
                                                 const int* __restrict__ offsets,
                                                 const int* __restrict__ bsum,
                                                 int* __restrict__ cursor0,
                                                 int* __restrict__ sorted_src,
                                                 int E, int nb1) {
    __shared__ int pre[64];
    scan_bsum_to_lds(bsum, nb1, pre);

    int e = ((int)blockIdx.x * 256 + (int)threadIdx.x) * 4;
    if (e + 4 <= E) {
        i32x4 d = *(const i32x4*)(dst + e);
        i32x4 s = *(const i32x4*)(src + e);
        int p0 = offsets[d.x] + pre[(d.x >> 11) & 63] + atomicAdd(&cursor0[d.x], 1);
        sorted_src[p0] = s.x;
        int p1 = offsets[d.y] + pre[(d.y >> 11) & 63] + atomicAdd(&cursor0[d.y], 1);
        sorted_src[p1] = s.y;
        int p2 = offsets[d.z] + pre[(d.z >> 11) & 63] + atomicAdd(&cursor0[d.z], 1);
        sorted_src[p2] = s.z;
        int p3 = offsets[d.w] + pre[(d.w >> 11) & 63] + atomicAdd(&cursor0[d.w], 1);
        sorted_src[p3] = s.w;
    } else {
        for (; e < E; ++e) {
            int t = dst[e];
            int p = offsets[t] + pre[(t >> 11) & 63] + atomicAdd(&cursor0[t], 1);
            sorted_src[p] = src[e];
        }
    }
}

// ---------------------------------------------------------------------------
// per node v (16 lanes x ushort8, f32 accum):
//   acc = h[v]*dinv[v] + sum_{CSR(v)} h[src]*dinv[src]
//   out[v] = relu(acc * dinv[v] + b)
__global__ __launch_bounds__(256) void k_aggregate(const unsigned short* __restrict__ hs,
                                                   const int* __restrict__ offsets,
                                                   const int* __restrict__ bsum,
                                                   const int* __restrict__ sorted_src,
                                                   const float* __restrict__ dinv,
                                                   const float* __restrict__ b,
                                                   float* __restrict__ out,
                                                   int N, int nb1) {
    __shared__ int pre[64];
    scan_bsum_to_lds(bsum, nb1, pre);

    int idx  = (int)blockIdx.x * 256 + (int)threadIdx.x;
    int v    = idx >> 4;
    int lane = idx & 15;
    if (v >= N) return;

    float dv = dinv[v];
    float acc[8];
    {
        us8 h = *(const us8*)(hs + (size_t)v * D + lane * 8);
#pragma unroll
        for (int j = 0; j < 8; ++j) acc[j] = bf2f(h[j]) * dv;   // self-loop term
    }

    int i   = offsets[v]     + pre[(v >> 11) & 63];
    int end = offsets[v + 1] + pre[((v + 1) >> 11) & 63];
    for (; i + 4 <= end; i += 4) {
        int s0 = sorted_src[i + 0];
        int s1 = sorted_src[i + 1];
        int s2 = sorted_src[i + 2];
        int s3 = sorted_src[i + 3];
        float d0 = dinv[s0], d1 = dinv[s1], d2 = dinv[s2], d3 = dinv[s3];
        us8 m0 = *(const us8*)(hs + (size_t)s0 * D + lane * 8);
        us8 m1 = *(const us8*)(hs + (size_t)s1 * D + lane * 8);
        us8 m2 = *(const us8*)(hs + (size_t)s2 * D + lane * 8);
        us8 m3 = *(const us8*)(hs + (size_t)s3 * D + lane * 8);
#pragma unroll
        for (int j = 0; j < 8; ++j)
            acc[j] += (bf2f(m0[j]) * d0 + bf2f(m1[j]) * d1)
                    + (bf2f(m2[j]) * d2 + bf2f(m3[j]) * d3);
    }
    for (; i < end; ++i) {
        int s = sorted_src[i];
        float ds = dinv[s];
        us8 m = *(const us8*)(hs + (size_t)s * D + lane * 8);
#pragma unroll
        for (int j = 0; j < 8; ++j) acc[j] += bf2f(m[j]) * ds;
    }

    f32x4 b0 = *(const f32x4*)(b + lane * 8);
    f32x4 b1 = *(const f32x4*)(b + lane * 8 + 4);
    f32x4 o0, o1;
#pragma unroll
    for (int j = 0; j < 4; ++j) {
        o0[j] = fmaxf(fmaf(acc[j],     dv, b0[j]), 0.0f);
        o1[j] = fmaxf(fmaf(acc[4 + j], dv, b1[j]), 0.0f);
    }
    float* op = out + (size_t)v * D + lane * 8;
    *(f32x4*)op       = o0;
    *(f32x4*)(op + 4) = o1;
}

// ---------------------------------------------------------------------------
static inline char* align_up(char* p, size_t a) {
    return (char*)(((uintptr_t)p + a - 1) & ~(uintptr_t)(a - 1));
}

extern "C" void kernel_launch(void* const* d_in, const int* in_sizes, int n_in,
                              void* d_out, int out_size, void* d_ws, size_t ws_size,
                              hipStream_t stream) {
    const float* x  = (const float*)d_in[0];   // [N, D]
    const float* W  = (const float*)d_in[1];   // [D, D]
    const float* b  = (const float*)d_in[2];   // [D]
    const int*   ei = (const int*)d_in[3];     // [2, E]

    const int N = in_sizes[0] / D;             // 50000
    const int E = in_sizes[3] / 2;             // 600000
    const int* src = ei;
    const int* dst = ei + E;

    // workspace layout (counts & cursor0 contiguous so one memset covers both;
    // N*4 = 200000 bytes is 64-aligned):
    // counts[N] cursor0[N] | offsets[N+1] bsum[64] sorted_src[E] (int)
    // dinv[N] (f32) | hs[N*D] (bf16)
    char* p = (char*)d_ws;
    int* counts        = (int*)p;              p = align_up(p + sizeof(int) * N * 2, 64);
    int* cursor0       = counts + N;
    int* offsets       = (int*)p;              p = align_up(p + sizeof(int) * (N + 1), 64);
    int* bsum          = (int*)p;              p = align_up(p + sizeof(int) * 64, 64);
    int* sorted_src    = (int*)p;              p = align_up(p + sizeof(int) * E, 64);
    float* dinv        = (float*)p;            p = align_up(p + sizeof(float) * N, 64);
    unsigned short* hs = (unsigned short*)p;

    float* out = (float*)d_out;

    const int nb1       = (N + 1 + SCAN_ELEMS - 1) / SCAN_ELEMS;  // 25 (<=64 required)
    const int gemm_blks = (N + 63) / 64;                          // 782
    const int hist_blks = (E / 4 + 255) / 256;                    // 586

    hipMemsetAsync(counts, 0, sizeof(int) * N * 2, stream);       // counts + cursor0
    k_gemm_hist<<<gemm_blks + hist_blks, 256, 0, stream>>>(x, W, dst, counts, hs, N, E, gemm_blks);
    k_scan1<<<nb1, 256, 0, stream>>>(counts, offsets, bsum, dinv, N);
    k_scatter<<<(E / 4 + 255) / 256, 256, 0, stream>>>(src, dst, offsets, bsum, cursor0, sorted_src, E, nb1);
    k_aggregate<<<(N * 16 + 255) / 256, 256, 0, stream>>>(hs, offsets, bsum, sorted_src, dinv, b, out, N, nb1);
}